// Round 17
// baseline (2079.121 us; speedup 1.0000x reference)
//
#include <hip/hip_runtime.h>
#include <hip/hip_bf16.h>
#include <stdint.h>

typedef short bf16x8 __attribute__((ext_vector_type(8)));
typedef float f32x4 __attribute__((ext_vector_type(4)));

static __device__ __forceinline__ unsigned short f32_to_bf16(float f) {
    union { float f; uint32_t u; } v; v.f = f;
    uint32_t u = v.u;
    uint32_t r = (u + 0x7FFFu + ((u >> 16) & 1u)) >> 16;
    return (unsigned short)r;
}

static __device__ __forceinline__ float bf16_to_f32(unsigned short s) {
    union { uint32_t u; float f; } c; c.u = ((uint32_t)s) << 16;
    return c.f;
}

// async global->LDS, 16B per lane (linear LDS dest: wave-uniform base + lane*16)
static __device__ __forceinline__ void gload_lds16(const unsigned short* g,
                                                   unsigned short* l) {
    __builtin_amdgcn_global_load_lds(
        (const __attribute__((address_space(1))) uint32_t*)g,
        (__attribute__((address_space(3))) uint32_t*)l, 16, 0, 0);
}

// barrier + compiler-level fence (s_barrier alone is not an IR memory fence).
static __device__ __forceinline__ void barrier_fenced() {
    __builtin_amdgcn_s_barrier();
    __builtin_amdgcn_sched_barrier(0);
    asm volatile("" ::: "memory");
}

// ---------------------------------------------------------------------------
// Kernel: convert fp32 -> bf16 (left, right), vectorized.
// ---------------------------------------------------------------------------
__global__ __launch_bounds__(256) void conv_bf16(
    const float* __restrict__ a, const float* __restrict__ b,
    unsigned short* __restrict__ oa, unsigned short* __restrict__ ob) {
    size_t i = ((size_t)blockIdx.x * 256 + threadIdx.x) * 4;
    const size_t stride = (size_t)gridDim.x * 256 * 4;
    for (; i < 16777216; i += stride) {
        float4 v = *reinterpret_cast<const float4*>(a + i);
        ushort4 o;
        o.x = f32_to_bf16(v.x); o.y = f32_to_bf16(v.y);
        o.z = f32_to_bf16(v.z); o.w = f32_to_bf16(v.w);
        *reinterpret_cast<ushort4*>(oa + i) = o;
        float4 u = *reinterpret_cast<const float4*>(b + i);
        ushort4 p;
        p.x = f32_to_bf16(u.x); p.y = f32_to_bf16(u.y);
        p.z = f32_to_bf16(u.z); p.w = f32_to_bf16(u.w);
        *reinterpret_cast<ushort4*>(ob + i) = p;
    }
}

// ---------------------------------------------------------------------------
// Kernel: transpose weights to bf16:  Wt[proj][n][k] = bf16(W[k][n])
// ---------------------------------------------------------------------------
__global__ void wtrans_kernel(const float* __restrict__ Wq,
                              const float* __restrict__ Wk,
                              const float* __restrict__ Wv,
                              unsigned short* __restrict__ Wt) {
    int proj = blockIdx.z;
    const float* W = (proj == 0) ? Wq : (proj == 1 ? Wk : Wv);
    unsigned short* out = Wt + (size_t)proj * 1024 * 1024;
    __shared__ float t[32][33];
    int k0 = blockIdx.x * 32, n0 = blockIdx.y * 32;
    int tx = threadIdx.x, ty = threadIdx.y; // 32 x 8
    for (int r = ty; r < 32; r += 8)
        t[r][tx] = W[(size_t)(k0 + r) * 1024 + n0 + tx];
    __syncthreads();
    for (int r = ty; r < 32; r += 8)
        out[(size_t)(n0 + r) * 1024 + k0 + tx] = f32_to_bf16(t[tx][r]);
}

// ---------------------------------------------------------------------------
// 256x256 GEMM core, BK=64 (round-12 proven): full-tile dbuf, vmcnt(0) drain,
// ONE fenced barrier per tile. Rotation swizzle (0 conflicts). 128 KiB LDS.
// ---------------------------------------------------------------------------
static __device__ __forceinline__ void gemm256_core(
    const unsigned short* __restrict__ A, const unsigned short* __restrict__ B,
    int K, int lda, int ldb, int m0, int n0,
    unsigned short* lds, f32x4 (&acc)[8][4]) {
    const int tid = threadIdx.x;
    const int lane = tid & 63;
    const int w = tid >> 6;
    const int wm = w >> 2, wn = w & 3;

    const int srow = tid >> 3;                       // 0..63
    const int scol = (((tid & 7) - srow) & 7) * 8;   // shorts
    const unsigned short* ga = A + (size_t)(m0 + srow) * lda + scol;
    const unsigned short* gb = B + (size_t)(n0 + srow) * ldb + scol;
    unsigned short* ldst = lds + tid * 8;

    const int pb = (((lane >> 4) + (lane & 7)) & 7) * 8;
    const int colk0 = pb, colk1 = pb ^ 32;
    const int rA0 = wm * 128 + (lane & 15);
    const int rB0 = wn * 64 + (lane & 15);

    const int NT = K >> 6;

#define STAGE8(gsA, gsB, pA, pB)                                    \
    gload_lds16((gsA), (pA));                                       \
    gload_lds16((gsA) + (size_t)64 * lda, (pA) + 4096);             \
    gload_lds16((gsA) + (size_t)128 * lda, (pA) + 8192);            \
    gload_lds16((gsA) + (size_t)192 * lda, (pA) + 12288);           \
    gload_lds16((gsB), (pB));                                       \
    gload_lds16((gsB) + (size_t)64 * ldb, (pB) + 4096);             \
    gload_lds16((gsB) + (size_t)128 * ldb, (pB) + 8192);            \
    gload_lds16((gsB) + (size_t)192 * ldb, (pB) + 12288);

    STAGE8(ga, gb, ldst, ldst + 16384);
    asm volatile("s_waitcnt vmcnt(0)" ::: "memory");
    barrier_fenced();

    int par = 0;
    for (int t = 0; t < NT; ++t) {
        const unsigned short* rA = lds + par * 32768;
        const unsigned short* rB = rA + 16384;
        bf16x8 a0[4][2], a1[4][2], b0[2][2], b1[2][2];

        if (t + 1 < NT) {
            const unsigned short* gan = ga + (t + 1) * 64;
            const unsigned short* gbn = gb + (t + 1) * 64;
            unsigned short* pA = ldst + (par ^ 1) * 32768;
            STAGE8(gan, gbn, pA, pA + 16384);
        }

#pragma unroll
        for (int mf = 0; mf < 4; ++mf) {
            a0[mf][0] = *reinterpret_cast<const bf16x8*>(
                &rA[(rA0 + mf * 16) * 64 + colk0]);
            a0[mf][1] = *reinterpret_cast<const bf16x8*>(
                &rA[(rA0 + mf * 16) * 64 + colk1]);
        }
#pragma unroll
        for (int nf = 0; nf < 2; ++nf) {
            b0[nf][0] = *reinterpret_cast<const bf16x8*>(
                &rB[(rB0 + nf * 16) * 64 + colk0]);
            b0[nf][1] = *reinterpret_cast<const bf16x8*>(
                &rB[(rB0 + nf * 16) * 64 + colk1]);
        }
        __builtin_amdgcn_s_setprio(1);
#pragma unroll
        for (int mf = 0; mf < 4; ++mf)
#pragma unroll
            for (int nf = 0; nf < 2; ++nf)
#pragma unroll
                for (int ks = 0; ks < 2; ++ks)
                    acc[mf][nf] = __builtin_amdgcn_mfma_f32_16x16x32_bf16(
                        a0[mf][ks], b0[nf][ks], acc[mf][nf], 0, 0, 0);
        __builtin_amdgcn_s_setprio(0);

#pragma unroll
        for (int nf = 0; nf < 2; ++nf) {
            b1[nf][0] = *reinterpret_cast<const bf16x8*>(
                &rB[(rB0 + 32 + nf * 16) * 64 + colk0]);
            b1[nf][1] = *reinterpret_cast<const bf16x8*>(
                &rB[(rB0 + 32 + nf * 16) * 64 + colk1]);
        }
        __builtin_amdgcn_s_setprio(1);
#pragma unroll
        for (int mf = 0; mf < 4; ++mf)
#pragma unroll
            for (int nf = 0; nf < 2; ++nf)
#pragma unroll
                for (int ks = 0; ks < 2; ++ks)
                    acc[mf][2 + nf] = __builtin_amdgcn_mfma_f32_16x16x32_bf16(
                        a0[mf][ks], b1[nf][ks], acc[mf][2 + nf], 0, 0, 0);
        __builtin_amdgcn_s_setprio(0);

#pragma unroll
        for (int mf = 0; mf < 4; ++mf) {
            a1[mf][0] = *reinterpret_cast<const bf16x8*>(
                &rA[(rA0 + 64 + mf * 16) * 64 + colk0]);
            a1[mf][1] = *reinterpret_cast<const bf16x8*>(
                &rA[(rA0 + 64 + mf * 16) * 64 + colk1]);
        }
        __builtin_amdgcn_s_setprio(1);
#pragma unroll
        for (int mf = 0; mf < 4; ++mf)
#pragma unroll
            for (int nf = 0; nf < 2; ++nf)
#pragma unroll
                for (int ks = 0; ks < 2; ++ks)
                    acc[4 + mf][nf] = __builtin_amdgcn_mfma_f32_16x16x32_bf16(
                        a1[mf][ks], b0[nf][ks], acc[4 + mf][nf], 0, 0, 0);
        __builtin_amdgcn_s_setprio(0);

        __builtin_amdgcn_s_setprio(1);
#pragma unroll
        for (int mf = 0; mf < 4; ++mf)
#pragma unroll
            for (int nf = 0; nf < 2; ++nf)
#pragma unroll
                for (int ks = 0; ks < 2; ++ks)
                    acc[4 + mf][2 + nf] = __builtin_amdgcn_mfma_f32_16x16x32_bf16(
                        a1[mf][ks], b1[nf][ks], acc[4 + mf][2 + nf], 0, 0, 0);
        __builtin_amdgcn_s_setprio(0);

        asm volatile("s_waitcnt vmcnt(0)" ::: "memory");
        barrier_fenced();
        par ^= 1;
    }
#undef STAGE8
}

// ---------------------------------------------------------------------------
// 256x256 GEMM core, BK=32: 64 KiB LDS -> 2 blocks/CU (cross-block overlap,
// the m97 mechanism). Same round-12 sync (full-tile dbuf, vmcnt(0) + one
// fenced barrier per tile). Same K-summation order as BK=64 core.
// Rotation swizzle for 64-B rows (4x 16B chunks): store chunk
// c = ((tid&3) - ((tid>>3)&3)) & 3 at slot tid&3 (row tid>>2; +128-row gload
// keeps c since 128>>1 == 0 mod 4); read position p = ((lane>>4) +
// ((lane&15)>>1)) & 3 — per-lane constant (all fragment row offsets are
// multiples of 16 -> row>>1 shifts by multiples of 8 == 0 mod 4).
// Bank check: within a 16-lane group each p value gets 4 lanes = 2 even-row
// + 2 odd-row -> 2 lanes/bank everywhere (free, m136).
// ---------------------------------------------------------------------------
static __device__ __forceinline__ void gemm256b_core(
    const unsigned short* __restrict__ A, const unsigned short* __restrict__ B,
    int K, int lda, int ldb, int m0, int n0,
    unsigned short* lds, f32x4 (&acc)[8][4]) {
    const int tid = threadIdx.x;
    const int lane = tid & 63;
    const int w = tid >> 6;
    const int wm = w >> 2, wn = w & 3;

    const int srow = tid >> 2;                                   // 0..127
    const int scol = (((tid & 3) - ((tid >> 3) & 3)) & 3) * 8;   // shorts
    const unsigned short* ga = A + (size_t)(m0 + srow) * lda + scol;
    const unsigned short* gb = B + (size_t)(n0 + srow) * ldb + scol;

    const int p = (((lane >> 4) + ((lane & 15) >> 1)) & 3) * 8;  // col shorts
    const int rA0 = wm * 128 + (lane & 15);
    const int rB0 = wn * 64 + (lane & 15);

    const int NT = K >> 5;

#define STAGE4(kt, pr)                                                        \
    { const unsigned short* gsA = ga + (size_t)(kt) * 32;                     \
      const unsigned short* gsB = gb + (size_t)(kt) * 32;                     \
      unsigned short* dA = lds + (pr) * 16384 + tid * 8;                      \
      unsigned short* dB = dA + 8192;                                         \
      gload_lds16(gsA, dA);                                                   \
      gload_lds16(gsA + (size_t)128 * lda, dA + 4096);                        \
      gload_lds16(gsB, dB);                                                   \
      gload_lds16(gsB + (size_t)128 * ldb, dB + 4096); }

    STAGE4(0, 0);
    asm volatile("s_waitcnt vmcnt(0)" ::: "memory");
    barrier_fenced();

    int par = 0;
    for (int t = 0; t < NT; ++t) {
        const unsigned short* rA = lds + par * 16384;
        const unsigned short* rB = rA + 8192;
        bf16x8 a0[4], a1[4], b0[2], b1[2];

        if (t + 1 < NT) STAGE4(t + 1, par ^ 1);

#pragma unroll
        for (int mf = 0; mf < 4; ++mf)
            a0[mf] = *reinterpret_cast<const bf16x8*>(
                &rA[(rA0 + mf * 16) * 32 + p]);
#pragma unroll
        for (int nf = 0; nf < 2; ++nf)
            b0[nf] = *reinterpret_cast<const bf16x8*>(
                &rB[(rB0 + nf * 16) * 32 + p]);
        __builtin_amdgcn_s_setprio(1);
#pragma unroll
        for (int mf = 0; mf < 4; ++mf)
#pragma unroll
            for (int nf = 0; nf < 2; ++nf)
                acc[mf][nf] = __builtin_amdgcn_mfma_f32_16x16x32_bf16(
                    a0[mf], b0[nf], acc[mf][nf], 0, 0, 0);
        __builtin_amdgcn_s_setprio(0);

#pragma unroll
        for (int nf = 0; nf < 2; ++nf)
            b1[nf] = *reinterpret_cast<const bf16x8*>(
                &rB[(rB0 + 32 + nf * 16) * 32 + p]);
        __builtin_amdgcn_s_setprio(1);
#pragma unroll
        for (int mf = 0; mf < 4; ++mf)
#pragma unroll
            for (int nf = 0; nf < 2; ++nf)
                acc[mf][2 + nf] = __builtin_amdgcn_mfma_f32_16x16x32_bf16(
                    a0[mf], b1[nf], acc[mf][2 + nf], 0, 0, 0);
        __builtin_amdgcn_s_setprio(0);

#pragma unroll
        for (int mf = 0; mf < 4; ++mf)
            a1[mf] = *reinterpret_cast<const bf16x8*>(
                &rA[(rA0 + 64 + mf * 16) * 32 + p]);
        __builtin_amdgcn_s_setprio(1);
#pragma unroll
        for (int mf = 0; mf < 4; ++mf)
#pragma unroll
            for (int nf = 0; nf < 2; ++nf)
                acc[4 + mf][nf] = __builtin_amdgcn_mfma_f32_16x16x32_bf16(
                    a1[mf], b0[nf], acc[4 + mf][nf], 0, 0, 0);
        __builtin_amdgcn_s_setprio(0);

        __builtin_amdgcn_s_setprio(1);
#pragma unroll
        for (int mf = 0; mf < 4; ++mf)
#pragma unroll
            for (int nf = 0; nf < 2; ++nf)
                acc[4 + mf][2 + nf] = __builtin_amdgcn_mfma_f32_16x16x32_bf16(
                    a1[mf], b1[nf], acc[4 + mf][2 + nf], 0, 0, 0);
        __builtin_amdgcn_s_setprio(0);

        asm volatile("s_waitcnt vmcnt(0)" ::: "memory");
        barrier_fenced();
        par ^= 1;
    }
#undef STAGE4
}

// ---------------------------------------------------------------------------
// proj256: Q = Xl@Wq, K = Xr@Wk, V = Xr@Wv (z = proj). M=16384, N=1024, K=1024.
// ---------------------------------------------------------------------------
__global__ __launch_bounds__(512, 2) void proj256(
    const unsigned short* __restrict__ Xl, const unsigned short* __restrict__ Xr,
    const unsigned short* __restrict__ Wt,
    unsigned short* __restrict__ Qb, unsigned short* __restrict__ Kb,
    unsigned short* __restrict__ Vt) {
    __shared__ unsigned short lds[65536];
    const int proj = blockIdx.z;
    const unsigned short* A = (proj == 0) ? Xl : Xr;
    const unsigned short* B = Wt + (size_t)proj * 1048576;
    const int m0 = blockIdx.x * 256, n0 = blockIdx.y * 256;

    f32x4 acc[8][4];
    for (int i = 0; i < 8; ++i)
        for (int j = 0; j < 4; ++j) acc[i][j] = {0.f, 0.f, 0.f, 0.f};

    gemm256_core(A, B, 1024, 1024, 1024, m0, n0, lds, acc);

    const int lane = threadIdx.x & 63, w = threadIdx.x >> 6;
    const int wm = w >> 2, wn = w & 3;
    if (proj < 2) {
        unsigned short* Out = (proj == 0) ? Qb : Kb;
        for (int mh = 0; mh < 2; ++mh)
            for (int mf = 0; mf < 4; ++mf)
                for (int nh = 0; nh < 2; ++nh)
                    for (int nf = 0; nf < 2; ++nf) {
                        f32x4 v = acc[mh * 4 + mf][nh * 2 + nf];
                        int row = m0 + wm * 128 + mh * 64 + mf * 16 + (lane >> 4) * 4;
                        int col = n0 + wn * 64 + nh * 32 + nf * 16 + (lane & 15);
                        for (int r = 0; r < 4; ++r)
                            Out[(size_t)(row + r) * 1024 + col] = f32_to_bf16(v[r]);
                    }
    } else {
        for (int mh = 0; mh < 2; ++mh)
            for (int mf = 0; mf < 4; ++mf)
                for (int nh = 0; nh < 2; ++nh)
                    for (int nf = 0; nf < 2; ++nf) {
                        f32x4 v = acc[mh * 4 + mf][nh * 2 + nf];
                        int row = m0 + wm * 128 + mh * 64 + mf * 16 + (lane >> 4) * 4;
                        int col = n0 + wn * 64 + nh * 32 + nf * 16 + (lane & 15);
                        int bb = row >> 12, jj = row & 4095;
                        uint32_t lo = f32_to_bf16(v[0]) |
                                      ((uint32_t)f32_to_bf16(v[1]) << 16);
                        uint32_t hi = f32_to_bf16(v[2]) |
                                      ((uint32_t)f32_to_bf16(v[3]) << 16);
                        *reinterpret_cast<uint2*>(
                            &Vt[((size_t)bb * 1024 + col) * 4096 + jj]) =
                            make_uint2(lo, hi);
                    }
    }
}

// ---------------------------------------------------------------------------
// qk256b: S[b] = Q[b] @ K[b]^T (bf16 logits), BK=32 core, 2 blocks/CU.
// ---------------------------------------------------------------------------
__global__ __launch_bounds__(512, 4) void qk256b(
    const unsigned short* __restrict__ Qb,
    const unsigned short* __restrict__ Kb,
    unsigned short* __restrict__ S) {
    __shared__ unsigned short lds[32768];
    const int b = blockIdx.z;
    const unsigned short* A = Qb + (size_t)b * 4194304;
    const unsigned short* B = Kb + (size_t)b * 4194304;
    unsigned short* Sp = S + (size_t)b * 16777216;
    const int m0 = blockIdx.x * 256, n0 = blockIdx.y * 256;

    f32x4 acc[8][4];
    for (int i = 0; i < 8; ++i)
        for (int j = 0; j < 4; ++j) acc[i][j] = {0.f, 0.f, 0.f, 0.f};

    gemm256b_core(A, B, 1024, 1024, 1024, m0, n0, lds, acc);

    const int lane = threadIdx.x & 63, w = threadIdx.x >> 6;
    const int wm = w >> 2, wn = w & 3;
    for (int mh = 0; mh < 2; ++mh)
        for (int mf = 0; mf < 4; ++mf)
            for (int nh = 0; nh < 2; ++nh)
                for (int nf = 0; nf < 2; ++nf) {
                    f32x4 v = acc[mh * 4 + mf][nh * 2 + nf];
                    int row = m0 + wm * 128 + mh * 64 + mf * 16 + (lane >> 4) * 4;
                    int col = n0 + wn * 64 + nh * 32 + nf * 16 + (lane & 15);
                    for (int r = 0; r < 4; ++r)
                        Sp[(size_t)(row + r) * 4096 + col] = f32_to_bf16(v[r]);
                }
}

// ---------------------------------------------------------------------------
// pv256b: out[b] = P[b] @ V[b] + left[b]. K=4096, BK=32 core, 2 blocks/CU.
// ---------------------------------------------------------------------------
__global__ __launch_bounds__(512, 4) void pv256b(
    const unsigned short* __restrict__ P,
    const unsigned short* __restrict__ Vt,
    const float* __restrict__ left,
    float* __restrict__ out) {
    __shared__ unsigned short lds[32768];
    const int b = blockIdx.z;
    const unsigned short* A = P + (size_t)b * 16777216;
    const unsigned short* B = Vt + (size_t)b * 4194304;
    const float* Lb = left + (size_t)b * 4194304;
    float* Ob = out + (size_t)b * 4194304;
    const int m0 = blockIdx.x * 256, n0 = blockIdx.y * 256;

    f32x4 acc[8][4];
    for (int i = 0; i < 8; ++i)
        for (int j = 0; j < 4; ++j) acc[i][j] = {0.f, 0.f, 0.f, 0.f};

    gemm256b_core(A, B, 4096, 4096, 4096, m0, n0, lds, acc);

    const int lane = threadIdx.x & 63, w = threadIdx.x >> 6;
    const int wm = w >> 2, wn = w & 3;
    for (int mh = 0; mh < 2; ++mh)
        for (int mf = 0; mf < 4; ++mf)
            for (int nh = 0; nh < 2; ++nh)
                for (int nf = 0; nf < 2; ++nf) {
                    f32x4 v = acc[mh * 4 + mf][nh * 2 + nf];
                    int row = m0 + wm * 128 + mh * 64 + mf * 16 + (lane >> 4) * 4;
                    int col = n0 + wn * 64 + nh * 32 + nf * 16 + (lane & 15);
                    for (int r = 0; r < 4; ++r) {
                        size_t off = (size_t)(row + r) * 1024 + col;
                        Ob[off] = v[r] + Lb[off];
                    }
                }
}

// ---------------------------------------------------------------------------
// Softmax rows (in-place on bf16 S; scale + 1/l folded).
// ---------------------------------------------------------------------------
__global__ __launch_bounds__(256, 4) void softmax_rows(
    unsigned short* __restrict__ S) {
    const int lane = threadIdx.x & 63;
    const int row = blockIdx.x * 4 + (threadIdx.x >> 6);
    unsigned short* r = S + (size_t)row * 4096;

    float f[64];
    float mx = -INFINITY;
    for (int i = 0; i < 8; ++i) {
        bf16x8 v = *reinterpret_cast<const bf16x8*>(&r[i * 512 + lane * 8]);
        for (int j = 0; j < 8; ++j) {
            float x = bf16_to_f32((unsigned short)v[j]);
            f[i * 8 + j] = x;
            mx = fmaxf(mx, x);
        }
    }
    for (int off = 32; off; off >>= 1) mx = fmaxf(mx, __shfl_xor(mx, off));
    const float ksc = 0.045084220f; // (1/sqrt(1024)) * log2(e)
    float sum = 0.f;
    for (int i = 0; i < 64; ++i) {
        f[i] = exp2f((f[i] - mx) * ksc);
        sum += f[i];
    }
    for (int off = 32; off; off >>= 1) sum += __shfl_xor(sum, off);
    float linv = 1.f / sum;
    for (int i = 0; i < 8; ++i) {
        bf16x8 v;
        for (int j = 0; j < 8; ++j)
            v[j] = (short)f32_to_bf16(f[i * 8 + j] * linv);
        *reinterpret_cast<bf16x8*>(&r[i * 512 + lane * 8]) = v;
    }
}

// ===========================================================================
// Fallback path (ws < 241 MB): round-6 proven kernels.
// ===========================================================================
__global__ __launch_bounds__(256, 4) void proj_gemm(
    const float* __restrict__ left, const float* __restrict__ right,
    const unsigned short* __restrict__ Wt,
    unsigned short* __restrict__ Qb, unsigned short* __restrict__ Kb,
    unsigned short* __restrict__ Vt) {
    const int proj = blockIdx.z;
    const float* A = (proj == 0) ? left : right;
    const unsigned short* Wn = Wt + (size_t)proj * 1024 * 1024;
    const int m0 = blockIdx.x * 128;
    const int n0 = blockIdx.y * 128;

    __shared__ unsigned short As[128][40];
    __shared__ unsigned short Bs[128][40];

    const int tid = threadIdx.x;
    const int lane = tid & 63, w = tid >> 6;
    const int wm = (w >> 1) * 64, wn = (w & 1) * 64;

    f32x4 acc[4][4];
    for (int i = 0; i < 4; ++i)
        for (int j = 0; j < 4; ++j) acc[i][j] = {0.f, 0.f, 0.f, 0.f};

    for (int k0 = 0; k0 < 1024; k0 += 32) {
        for (int p = 0; p < 4; ++p) {
            int r = p * 32 + (tid >> 3);
            int c = (tid & 7) * 4;
            float4 v = *reinterpret_cast<const float4*>(
                &A[(size_t)(m0 + r) * 1024 + k0 + c]);
            uint32_t lo = f32_to_bf16(v.x) | ((uint32_t)f32_to_bf16(v.y) << 16);
            uint32_t hi = f32_to_bf16(v.z) | ((uint32_t)f32_to_bf16(v.w) << 16);
            *reinterpret_cast<uint2*>(&As[r][c]) = make_uint2(lo, hi);
        }
        for (int cc = 0; cc < 2; ++cc) {
            int idx = tid * 2 + cc;
            int n = idx >> 2, ch = (idx & 3) * 8;
            bf16x8 v = *reinterpret_cast<const bf16x8*>(
                &Wn[(size_t)(n0 + n) * 1024 + k0 + ch]);
            *reinterpret_cast<bf16x8*>(&Bs[n][ch]) = v;
        }
        __syncthreads();
        bf16x8 af[4], bfr[4];
        for (int i = 0; i < 4; ++i)
            af[i] = *reinterpret_cast<const bf16x8*>(
                &As[wm + i * 16 + (lane & 15)][(lane >> 4) * 8]);
        for (int j = 0; j < 4; ++j)
            bfr[j] = *reinterpret_cast<const bf16x8*>(
                &Bs[wn + j * 16 + (lane & 15)][(lane >> 4) * 8]);
        for (int i = 0; i < 4; ++i)
            for (int j = 0; j < 4; ++j)
                acc[i][j] = __builtin_amdgcn_mfma_f32_16x16x32_bf16(
                    af[i], bfr[j], acc[i][j], 0, 0, 0);
        __syncthreads();
    }

    if (proj < 2) {
        unsigned short* Out = (proj == 0) ? Qb : Kb;
        for (int i = 0; i < 4; ++i)
            for (int j = 0; j < 4; ++j) {
                int col = n0 + wn + j * 16 + (lane & 15);
                int row = m0 + wm + i * 16 + (lane >> 4) * 4;
                for (int r = 0; r < 4; ++r)
                    Out[(size_t)(row + r) * 1024 + col] = f32_to_bf16(acc[i][j][r]);
            }
    } else {
        for (int i = 0; i < 4; ++i)
            for (int j = 0; j < 4; ++j) {
                int col = n0 + wn + j * 16 + (lane & 15);
                int row = m0 + wm + i * 16 + (lane >> 4) * 4;
                int b = row >> 12, jj = row & 4095;
                uint32_t lo = f32_to_bf16(acc[i][j][0]) |
                              ((uint32_t)f32_to_bf16(acc[i][j][1]) << 16);
                uint32_t hi = f32_to_bf16(acc[i][j][2]) |
                              ((uint32_t)f32_to_bf16(acc[i][j][3]) << 16);
                *reinterpret_cast<uint2*>(
                    &Vt[((size_t)b * 1024 + col) * 4096 + jj]) = make_uint2(lo, hi);
            }
    }
}

template <int K, int LDA, int LDB>
static __device__ __forceinline__ void gemm_core(
    const unsigned short* __restrict__ A, const unsigned short* __restrict__ B,
    unsigned short* As, unsigned short* Bs, int m0, int n0, f32x4 (&acc)[4][4]) {
    const int tid = threadIdx.x;
    const int lane = tid & 63, w = tid >> 6;
    const int wm = (w >> 1) * 64, wn = (w & 1) * 64;
    const int r0 = tid >> 2, c0 = (tid & 3) * 8;

    const unsigned short* a0 = &A[(size_t)(m0 + r0) * LDA + c0];
    const unsigned short* a1 = a0 + (size_t)64 * LDA;
    const unsigned short* b0 = &B[(size_t)(n0 + r0) * LDB + c0];
    const unsigned short* b1 = b0 + (size_t)64 * LDB;
    unsigned short* asl = As + tid * 8;
    unsigned short* bsl = Bs + tid * 8;

    for (int k0 = 0; k0 < K; k0 += 32) {
        gload_lds16(a0 + k0, asl);
        gload_lds16(a1 + k0, asl + 2048);
        gload_lds16(b0 + k0, bsl);
        gload_lds16(b1 + k0, bsl + 2048);
        __syncthreads();
        bf16x8 af[4], bfr[4];
#pragma unroll
        for (int i = 0; i < 4; ++i)
            af[i] = *reinterpret_cast<const bf16x8*>(
                &As[(wm + i * 16 + (lane & 15)) * 32 + (lane >> 4) * 8]);
#pragma unroll
        for (int j = 0; j < 4; ++j)
            bfr[j] = *reinterpret_cast<const bf16x8*>(
                &Bs[(wn + j * 16 + (lane & 15)) * 32 + (lane >> 4) * 8]);
#pragma unroll
        for (int i = 0; i < 4; ++i)
#pragma unroll
            for (int j = 0; j < 4; ++j)
                acc[i][j] = __builtin_amdgcn_mfma_f32_16x16x32_bf16(
                    af[i], bfr[j], acc[i][j], 0, 0, 0);
        __syncthreads();
    }
}

__global__ __launch_bounds__(256, 2) void qk_gemm(
    const unsigned short* __restrict__ Qb,
    const unsigned short* __restrict__ Kb,
    unsigned short* __restrict__ S) {
    const unsigned short* A = Qb;
    const unsigned short* B = Kb;
    const int m0 = blockIdx.x * 128, n0 = blockIdx.y * 128;

    __shared__ unsigned short As[128 * 32];
    __shared__ unsigned short Bs[128 * 32];

    const int tid = threadIdx.x;
    const int lane = tid & 63, w = tid >> 6;
    const int wm = (w >> 1) * 64, wn = (w & 1) * 64;

    f32x4 acc[4][4];
    for (int i = 0; i < 4; ++i)
        for (int j = 0; j < 4; ++j) acc[i][j] = {0.f, 0.f, 0.f, 0.f};

    gemm_core<1024, 1024, 1024>(A, B, As, Bs, m0, n0, acc);

    for (int i = 0; i < 4; ++i)
        for (int j = 0; j < 4; ++j) {
            int col = n0 + wn + j * 16 + (lane & 15);
            int row = m0 + wm + i * 16 + (lane >> 4) * 4;
            for (int r = 0; r < 4; ++r)
                S[(size_t)(row + r) * 4096 + col] = f32_to_bf16(acc[i][j][r]);
        }
}

__global__ __launch_bounds__(256, 2) void pv_gemm(
    const unsigned short* __restrict__ P,
    const unsigned short* __restrict__ Vt,
    const float* __restrict__ left,
    float* __restrict__ out) {
    const int m0 = blockIdx.x * 128, n0 = blockIdx.y * 128;

    __shared__ unsigned short As[128 * 32];
    __shared__ unsigned short Bs[128 * 32];

    const int tid = threadIdx.x;
    const int lane = tid & 63, w = tid >> 6;
    const int wm = (w >> 1) * 64, wn = (w & 1) * 64;

    f32x4 acc[4][4];
    for (int i = 0; i < 4; ++i)
        for (int j = 0; j < 4; ++j) acc[i][j] = {0.f, 0.f, 0.f, 0.f};

    gemm_core<4096, 4096, 4096>(P, Vt, As, Bs, m0, n0, acc);

    for (int i = 0; i < 4; ++i)
        for (int j = 0; j < 4; ++j) {
            int col = n0 + wn + j * 16 + (lane & 15);
            int row = m0 + wm + i * 16 + (lane >> 4) * 4;
            for (int r = 0; r < 4; ++r) {
                size_t off = (size_t)(row + r) * 1024 + col;
                out[off] = acc[i][j][r] + left[off];
            }
        }
}

// ---------------------------------------------------------------------------
extern "C" void kernel_launch(void* const* d_in, const int* in_sizes, int n_in,
                              void* d_out, int out_size, void* d_ws, size_t ws_size,
                              hipStream_t stream) {
    const float* left  = (const float*)d_in[0];
    const float* right = (const float*)d_in[1];
    const float* Wq    = (const float*)d_in[2];
    const float* Wk    = (const float*)d_in[3];
    const float* Wv    = (const float*)d_in[4];
    float* out = (float*)d_out;

    // layout: Wt 6MB | Qb 32MB | Kb 32MB | Vt 32MB | S 128MB (Xl/Xr overlay S)
    char* ws = (char*)d_ws;
    unsigned short* Wt = (unsigned short*)ws;
    unsigned short* Qb = (unsigned short*)(ws + 6291456);
    unsigned short* Kb = Qb + (size_t)16384 * 1024;
    unsigned short* Vt = Kb + (size_t)16384 * 1024;
    unsigned short* Sb = Vt + (size_t)16384 * 1024;
    unsigned short* Xl = Sb;                 // dead once qk starts
    unsigned short* Xr = Sb + 16777216;

    const bool batched = ws_size >= 241172480ull; // 6MB + 3*32MB + 128MB

    wtrans_kernel<<<dim3(32, 32, 3), dim3(32, 8), 0, stream>>>(Wq, Wk, Wv, Wt);

    if (batched) {
        conv_bf16<<<4096, 256, 0, stream>>>(left, right, Xl, Xr);
        proj256<<<dim3(64, 4, 3), 512, 0, stream>>>(Xl, Xr, Wt, Qb, Kb, Vt);
        qk256b<<<dim3(16, 16, 4), 512, 0, stream>>>(Qb, Kb, Sb);
        softmax_rows<<<4096, 256, 0, stream>>>(Sb);
        pv256b<<<dim3(16, 4, 4), 512, 0, stream>>>(Sb, Vt, left, out);
    } else {
        proj_gemm<<<dim3(128, 8, 3), 256, 0, stream>>>(left, right, Wt, Qb, Kb, Vt);
        for (int b = 0; b < 4; ++b) {
            qk_gemm<<<dim3(32, 32, 1), 256, 0, stream>>>(
                Qb + (size_t)b * 4194304, Kb + (size_t)b * 4194304, Sb);
            softmax_rows<<<1024, 256, 0, stream>>>(Sb);
            pv_gemm<<<dim3(32, 8, 1), 256, 0, stream>>>(
                Sb, Vt + (size_t)b * 4194304,
                left + (size_t)b * 4194304, out + (size_t)b * 4194304);
        }
    }
}

// Round 19
// 467.554 us; speedup vs baseline: 4.4468x; 4.4468x over previous
//
#include <hip/hip_runtime.h>
#include <hip/hip_bf16.h>
#include <stdint.h>

typedef short bf16x8 __attribute__((ext_vector_type(8)));
typedef float f32x4 __attribute__((ext_vector_type(4)));

static __device__ __forceinline__ unsigned short f32_to_bf16(float f) {
    union { float f; uint32_t u; } v; v.f = f;
    uint32_t u = v.u;
    uint32_t r = (u + 0x7FFFu + ((u >> 16) & 1u)) >> 16;
    return (unsigned short)r;
}

static __device__ __forceinline__ float bf16_to_f32(unsigned short s) {
    union { uint32_t u; float f; } c; c.u = ((uint32_t)s) << 16;
    return c.f;
}

// async global->LDS, 16B per lane (linear LDS dest: wave-uniform base + lane*16)
static __device__ __forceinline__ void gload_lds16(const unsigned short* g,
                                                   unsigned short* l) {
    __builtin_amdgcn_global_load_lds(
        (const __attribute__((address_space(1))) uint32_t*)g,
        (__attribute__((address_space(3))) uint32_t*)l, 16, 0, 0);
}

// barrier + compiler-level fence (s_barrier alone is not an IR memory fence).
static __device__ __forceinline__ void barrier_fenced() {
    __builtin_amdgcn_s_barrier();
    __builtin_amdgcn_sched_barrier(0);
    asm volatile("" ::: "memory");
}

// ---------------------------------------------------------------------------
// Kernel: convert fp32 -> bf16 (left, right), vectorized.
// ---------------------------------------------------------------------------
__global__ __launch_bounds__(256) void conv_bf16(
    const float* __restrict__ a, const float* __restrict__ b,
    unsigned short* __restrict__ oa, unsigned short* __restrict__ ob) {
    size_t i = ((size_t)blockIdx.x * 256 + threadIdx.x) * 4;
    const size_t stride = (size_t)gridDim.x * 256 * 4;
    for (; i < 16777216; i += stride) {
        float4 v = *reinterpret_cast<const float4*>(a + i);
        ushort4 o;
        o.x = f32_to_bf16(v.x); o.y = f32_to_bf16(v.y);
        o.z = f32_to_bf16(v.z); o.w = f32_to_bf16(v.w);
        *reinterpret_cast<ushort4*>(oa + i) = o;
        float4 u = *reinterpret_cast<const float4*>(b + i);
        ushort4 p;
        p.x = f32_to_bf16(u.x); p.y = f32_to_bf16(u.y);
        p.z = f32_to_bf16(u.z); p.w = f32_to_bf16(u.w);
        *reinterpret_cast<ushort4*>(ob + i) = p;
    }
}

// ---------------------------------------------------------------------------
// Kernel: transpose weights to bf16:  Wt[proj][n][k] = bf16(W[k][n])
// ---------------------------------------------------------------------------
__global__ void wtrans_kernel(const float* __restrict__ Wq,
                              const float* __restrict__ Wk,
                              const float* __restrict__ Wv,
                              unsigned short* __restrict__ Wt) {
    int proj = blockIdx.z;
    const float* W = (proj == 0) ? Wq : (proj == 1 ? Wk : Wv);
    unsigned short* out = Wt + (size_t)proj * 1024 * 1024;
    __shared__ float t[32][33];
    int k0 = blockIdx.x * 32, n0 = blockIdx.y * 32;
    int tx = threadIdx.x, ty = threadIdx.y; // 32 x 8
    for (int r = ty; r < 32; r += 8)
        t[r][tx] = W[(size_t)(k0 + r) * 1024 + n0 + tx];
    __syncthreads();
    for (int r = ty; r < 32; r += 8)
        out[(size_t)(n0 + r) * 1024 + k0 + tx] = f32_to_bf16(t[tx][r]);
}

// ---------------------------------------------------------------------------
// 256x256 GEMM core, BK=64 (round-12 proven): full-tile dbuf, vmcnt(0) drain,
// ONE fenced barrier per tile. Rotation swizzle (0 conflicts). 128 KiB LDS.
// ---------------------------------------------------------------------------
static __device__ __forceinline__ void gemm256_core(
    const unsigned short* __restrict__ A, const unsigned short* __restrict__ B,
    int K, int lda, int ldb, int m0, int n0,
    unsigned short* lds, f32x4 (&acc)[8][4]) {
    const int tid = threadIdx.x;
    const int lane = tid & 63;
    const int w = tid >> 6;
    const int wm = w >> 2, wn = w & 3;

    const int srow = tid >> 3;                       // 0..63
    const int scol = (((tid & 7) - srow) & 7) * 8;   // shorts
    const unsigned short* ga = A + (size_t)(m0 + srow) * lda + scol;
    const unsigned short* gb = B + (size_t)(n0 + srow) * ldb + scol;
    unsigned short* ldst = lds + tid * 8;

    const int pb = (((lane >> 4) + (lane & 7)) & 7) * 8;
    const int colk0 = pb, colk1 = pb ^ 32;
    const int rA0 = wm * 128 + (lane & 15);
    const int rB0 = wn * 64 + (lane & 15);

    const int NT = K >> 6;

#define STAGE8(gsA, gsB, pA, pB)                                    \
    gload_lds16((gsA), (pA));                                       \
    gload_lds16((gsA) + (size_t)64 * lda, (pA) + 4096);             \
    gload_lds16((gsA) + (size_t)128 * lda, (pA) + 8192);            \
    gload_lds16((gsA) + (size_t)192 * lda, (pA) + 12288);           \
    gload_lds16((gsB), (pB));                                       \
    gload_lds16((gsB) + (size_t)64 * ldb, (pB) + 4096);             \
    gload_lds16((gsB) + (size_t)128 * ldb, (pB) + 8192);            \
    gload_lds16((gsB) + (size_t)192 * ldb, (pB) + 12288);

    STAGE8(ga, gb, ldst, ldst + 16384);
    asm volatile("s_waitcnt vmcnt(0)" ::: "memory");
    barrier_fenced();

    int par = 0;
    for (int t = 0; t < NT; ++t) {
        const unsigned short* rA = lds + par * 32768;
        const unsigned short* rB = rA + 16384;
        bf16x8 a0[4][2], a1[4][2], b0[2][2], b1[2][2];

        if (t + 1 < NT) {
            const unsigned short* gan = ga + (t + 1) * 64;
            const unsigned short* gbn = gb + (t + 1) * 64;
            unsigned short* pA = ldst + (par ^ 1) * 32768;
            STAGE8(gan, gbn, pA, pA + 16384);
        }

#pragma unroll
        for (int mf = 0; mf < 4; ++mf) {
            a0[mf][0] = *reinterpret_cast<const bf16x8*>(
                &rA[(rA0 + mf * 16) * 64 + colk0]);
            a0[mf][1] = *reinterpret_cast<const bf16x8*>(
                &rA[(rA0 + mf * 16) * 64 + colk1]);
        }
#pragma unroll
        for (int nf = 0; nf < 2; ++nf) {
            b0[nf][0] = *reinterpret_cast<const bf16x8*>(
                &rB[(rB0 + nf * 16) * 64 + colk0]);
            b0[nf][1] = *reinterpret_cast<const bf16x8*>(
                &rB[(rB0 + nf * 16) * 64 + colk1]);
        }
        __builtin_amdgcn_s_setprio(1);
#pragma unroll
        for (int mf = 0; mf < 4; ++mf)
#pragma unroll
            for (int nf = 0; nf < 2; ++nf)
#pragma unroll
                for (int ks = 0; ks < 2; ++ks)
                    acc[mf][nf] = __builtin_amdgcn_mfma_f32_16x16x32_bf16(
                        a0[mf][ks], b0[nf][ks], acc[mf][nf], 0, 0, 0);
        __builtin_amdgcn_s_setprio(0);

#pragma unroll
        for (int nf = 0; nf < 2; ++nf) {
            b1[nf][0] = *reinterpret_cast<const bf16x8*>(
                &rB[(rB0 + 32 + nf * 16) * 64 + colk0]);
            b1[nf][1] = *reinterpret_cast<const bf16x8*>(
                &rB[(rB0 + 32 + nf * 16) * 64 + colk1]);
        }
        __builtin_amdgcn_s_setprio(1);
#pragma unroll
        for (int mf = 0; mf < 4; ++mf)
#pragma unroll
            for (int nf = 0; nf < 2; ++nf)
#pragma unroll
                for (int ks = 0; ks < 2; ++ks)
                    acc[mf][2 + nf] = __builtin_amdgcn_mfma_f32_16x16x32_bf16(
                        a0[mf][ks], b1[nf][ks], acc[mf][2 + nf], 0, 0, 0);
        __builtin_amdgcn_s_setprio(0);

#pragma unroll
        for (int mf = 0; mf < 4; ++mf) {
            a1[mf][0] = *reinterpret_cast<const bf16x8*>(
                &rA[(rA0 + 64 + mf * 16) * 64 + colk0]);
            a1[mf][1] = *reinterpret_cast<const bf16x8*>(
                &rA[(rA0 + 64 + mf * 16) * 64 + colk1]);
        }
        __builtin_amdgcn_s_setprio(1);
#pragma unroll
        for (int mf = 0; mf < 4; ++mf)
#pragma unroll
            for (int nf = 0; nf < 2; ++nf)
#pragma unroll
                for (int ks = 0; ks < 2; ++ks)
                    acc[4 + mf][nf] = __builtin_amdgcn_mfma_f32_16x16x32_bf16(
                        a1[mf][ks], b0[nf][ks], acc[4 + mf][nf], 0, 0, 0);
        __builtin_amdgcn_s_setprio(0);

        __builtin_amdgcn_s_setprio(1);
#pragma unroll
        for (int mf = 0; mf < 4; ++mf)
#pragma unroll
            for (int nf = 0; nf < 2; ++nf)
#pragma unroll
                for (int ks = 0; ks < 2; ++ks)
                    acc[4 + mf][2 + nf] = __builtin_amdgcn_mfma_f32_16x16x32_bf16(
                        a1[mf][ks], b1[nf][ks], acc[4 + mf][2 + nf], 0, 0, 0);
        __builtin_amdgcn_s_setprio(0);

        asm volatile("s_waitcnt vmcnt(0)" ::: "memory");
        barrier_fenced();
        par ^= 1;
    }
#undef STAGE8
}

// ---------------------------------------------------------------------------
// m97-style 128x128 GEMM core: BK=32, linear LDS, global_load_lds x4,
// 2 barriers per K-step, 256 threads (4 waves, 64x64 each), 16 KiB LDS ->
// ~4 blocks/CU (cross-block MFMA/VMEM overlap — the m97 mechanism).
// Measured round 6: batched qk at ~122 us (vs 147.9 for the 256-sq core).
// ---------------------------------------------------------------------------
template <int K, int LDA, int LDB>
static __device__ __forceinline__ void gemm_core(
    const unsigned short* __restrict__ A, const unsigned short* __restrict__ B,
    unsigned short* As, unsigned short* Bs, int m0, int n0, f32x4 (&acc)[4][4]) {
    const int tid = threadIdx.x;
    const int lane = tid & 63, w = tid >> 6;
    const int wm = (w >> 1) * 64, wn = (w & 1) * 64;
    const int r0 = tid >> 2, c0 = (tid & 3) * 8;

    const unsigned short* a0 = &A[(size_t)(m0 + r0) * LDA + c0];
    const unsigned short* a1 = a0 + (size_t)64 * LDA;
    const unsigned short* b0 = &B[(size_t)(n0 + r0) * LDB + c0];
    const unsigned short* b1 = b0 + (size_t)64 * LDB;
    unsigned short* asl = As + tid * 8;
    unsigned short* bsl = Bs + tid * 8;

    for (int k0 = 0; k0 < K; k0 += 32) {
        gload_lds16(a0 + k0, asl);
        gload_lds16(a1 + k0, asl + 2048);
        gload_lds16(b0 + k0, bsl);
        gload_lds16(b1 + k0, bsl + 2048);
        __syncthreads();
        bf16x8 af[4], bfr[4];
#pragma unroll
        for (int i = 0; i < 4; ++i)
            af[i] = *reinterpret_cast<const bf16x8*>(
                &As[(wm + i * 16 + (lane & 15)) * 32 + (lane >> 4) * 8]);
#pragma unroll
        for (int j = 0; j < 4; ++j)
            bfr[j] = *reinterpret_cast<const bf16x8*>(
                &Bs[(wn + j * 16 + (lane & 15)) * 32 + (lane >> 4) * 8]);
#pragma unroll
        for (int i = 0; i < 4; ++i)
#pragma unroll
            for (int j = 0; j < 4; ++j)
                acc[i][j] = __builtin_amdgcn_mfma_f32_16x16x32_bf16(
                    af[i], bfr[j], acc[i][j], 0, 0, 0);
        __syncthreads();
    }
}

// ---------------------------------------------------------------------------
// proj256: Q = Xl@Wq, K = Xr@Wk, V = Xr@Wv (z = proj). M=16384, N=1024, K=1024.
// ---------------------------------------------------------------------------
__global__ __launch_bounds__(512, 2) void proj256(
    const unsigned short* __restrict__ Xl, const unsigned short* __restrict__ Xr,
    const unsigned short* __restrict__ Wt,
    unsigned short* __restrict__ Qb, unsigned short* __restrict__ Kb,
    unsigned short* __restrict__ Vt) {
    __shared__ unsigned short lds[65536];
    const int proj = blockIdx.z;
    const unsigned short* A = (proj == 0) ? Xl : Xr;
    const unsigned short* B = Wt + (size_t)proj * 1048576;
    const int m0 = blockIdx.x * 256, n0 = blockIdx.y * 256;

    f32x4 acc[8][4];
    for (int i = 0; i < 8; ++i)
        for (int j = 0; j < 4; ++j) acc[i][j] = {0.f, 0.f, 0.f, 0.f};

    gemm256_core(A, B, 1024, 1024, 1024, m0, n0, lds, acc);

    const int lane = threadIdx.x & 63, w = threadIdx.x >> 6;
    const int wm = w >> 2, wn = w & 3;
    if (proj < 2) {
        unsigned short* Out = (proj == 0) ? Qb : Kb;
        for (int mh = 0; mh < 2; ++mh)
            for (int mf = 0; mf < 4; ++mf)
                for (int nh = 0; nh < 2; ++nh)
                    for (int nf = 0; nf < 2; ++nf) {
                        f32x4 v = acc[mh * 4 + mf][nh * 2 + nf];
                        int row = m0 + wm * 128 + mh * 64 + mf * 16 + (lane >> 4) * 4;
                        int col = n0 + wn * 64 + nh * 32 + nf * 16 + (lane & 15);
                        for (int r = 0; r < 4; ++r)
                            Out[(size_t)(row + r) * 1024 + col] = f32_to_bf16(v[r]);
                    }
    } else {
        for (int mh = 0; mh < 2; ++mh)
            for (int mf = 0; mf < 4; ++mf)
                for (int nh = 0; nh < 2; ++nh)
                    for (int nf = 0; nf < 2; ++nf) {
                        f32x4 v = acc[mh * 4 + mf][nh * 2 + nf];
                        int row = m0 + wm * 128 + mh * 64 + mf * 16 + (lane >> 4) * 4;
                        int col = n0 + wn * 64 + nh * 32 + nf * 16 + (lane & 15);
                        int bb = row >> 12, jj = row & 4095;
                        uint32_t lo = f32_to_bf16(v[0]) |
                                      ((uint32_t)f32_to_bf16(v[1]) << 16);
                        uint32_t hi = f32_to_bf16(v[2]) |
                                      ((uint32_t)f32_to_bf16(v[3]) << 16);
                        *reinterpret_cast<uint2*>(
                            &Vt[((size_t)bb * 1024 + col) * 4096 + jj]) =
                            make_uint2(lo, hi);
                    }
    }
}

// ---------------------------------------------------------------------------
// qk128: S[b] = Q[b] @ K[b]^T (bf16 logits). m97 128-sq core, z = batch.
// Round-6 measured ~122 us for the full batched dispatch.
// ---------------------------------------------------------------------------
__global__ __launch_bounds__(256, 2) void qk128(
    const unsigned short* __restrict__ Qb,
    const unsigned short* __restrict__ Kb,
    unsigned short* __restrict__ S) {
    const int b = blockIdx.z;
    const unsigned short* A = Qb + (size_t)b * 4194304;
    const unsigned short* B = Kb + (size_t)b * 4194304;
    unsigned short* Sp = S + (size_t)b * 16777216;
    const int m0 = blockIdx.x * 128, n0 = blockIdx.y * 128;

    __shared__ unsigned short As[128 * 32];
    __shared__ unsigned short Bs[128 * 32];

    const int tid = threadIdx.x;
    const int lane = tid & 63, w = tid >> 6;
    const int wm = (w >> 1) * 64, wn = (w & 1) * 64;

    f32x4 acc[4][4];
    for (int i = 0; i < 4; ++i)
        for (int j = 0; j < 4; ++j) acc[i][j] = {0.f, 0.f, 0.f, 0.f};

    gemm_core<1024, 1024, 1024>(A, B, As, Bs, m0, n0, acc);

    for (int i = 0; i < 4; ++i)
        for (int j = 0; j < 4; ++j) {
            int col = n0 + wn + j * 16 + (lane & 15);
            int row = m0 + wm + i * 16 + (lane >> 4) * 4;
            for (int r = 0; r < 4; ++r)
                Sp[(size_t)(row + r) * 4096 + col] = f32_to_bf16(acc[i][j][r]);
        }
}

// ---------------------------------------------------------------------------
// pv256: out[b] = P[b] @ V[b] + left[b]. K=4096, round-12 core. z = batch.
// ---------------------------------------------------------------------------
__global__ __launch_bounds__(512, 2) void pv256(
    const unsigned short* __restrict__ P,
    const unsigned short* __restrict__ Vt,
    const float* __restrict__ left,
    float* __restrict__ out) {
    __shared__ unsigned short lds[65536];
    const int b = blockIdx.z;
    const unsigned short* A = P + (size_t)b * 16777216;
    const unsigned short* B = Vt + (size_t)b * 4194304;
    const float* Lb = left + (size_t)b * 4194304;
    float* Ob = out + (size_t)b * 4194304;
    const int m0 = blockIdx.x * 256, n0 = blockIdx.y * 256;

    f32x4 acc[8][4];
    for (int i = 0; i < 8; ++i)
        for (int j = 0; j < 4; ++j) acc[i][j] = {0.f, 0.f, 0.f, 0.f};

    gemm256_core(A, B, 4096, 4096, 4096, m0, n0, lds, acc);

    const int lane = threadIdx.x & 63, w = threadIdx.x >> 6;
    const int wm = w >> 2, wn = w & 3;
    for (int mh = 0; mh < 2; ++mh)
        for (int mf = 0; mf < 4; ++mf)
            for (int nh = 0; nh < 2; ++nh)
                for (int nf = 0; nf < 2; ++nf) {
                    f32x4 v = acc[mh * 4 + mf][nh * 2 + nf];
                    int row = m0 + wm * 128 + mh * 64 + mf * 16 + (lane >> 4) * 4;
                    int col = n0 + wn * 64 + nh * 32 + nf * 16 + (lane & 15);
                    for (int r = 0; r < 4; ++r) {
                        size_t off = (size_t)(row + r) * 1024 + col;
                        Ob[off] = v[r] + Lb[off];
                    }
                }
}

// ---------------------------------------------------------------------------
// Softmax rows (in-place on bf16 S; scale + 1/l folded).
// ---------------------------------------------------------------------------
__global__ __launch_bounds__(256, 4) void softmax_rows(
    unsigned short* __restrict__ S) {
    const int lane = threadIdx.x & 63;
    const int row = blockIdx.x * 4 + (threadIdx.x >> 6);
    unsigned short* r = S + (size_t)row * 4096;

    float f[64];
    float mx = -INFINITY;
    for (int i = 0; i < 8; ++i) {
        bf16x8 v = *reinterpret_cast<const bf16x8*>(&r[i * 512 + lane * 8]);
        for (int j = 0; j < 8; ++j) {
            float x = bf16_to_f32((unsigned short)v[j]);
            f[i * 8 + j] = x;
            mx = fmaxf(mx, x);
        }
    }
    for (int off = 32; off; off >>= 1) mx = fmaxf(mx, __shfl_xor(mx, off));
    const float ksc = 0.045084220f; // (1/sqrt(1024)) * log2(e)
    float sum = 0.f;
    for (int i = 0; i < 64; ++i) {
        f[i] = exp2f((f[i] - mx) * ksc);
        sum += f[i];
    }
    for (int off = 32; off; off >>= 1) sum += __shfl_xor(sum, off);
    float linv = 1.f / sum;
    for (int i = 0; i < 8; ++i) {
        bf16x8 v;
        for (int j = 0; j < 8; ++j)
            v[j] = (short)f32_to_bf16(f[i * 8 + j] * linv);
        *reinterpret_cast<bf16x8*>(&r[i * 512 + lane * 8]) = v;
    }
}

// ===========================================================================
// Fallback path (ws < 241 MB): round-6 proven kernels.
// ===========================================================================
__global__ __launch_bounds__(256, 4) void proj_gemm(
    const float* __restrict__ left, const float* __restrict__ right,
    const unsigned short* __restrict__ Wt,
    unsigned short* __restrict__ Qb, unsigned short* __restrict__ Kb,
    unsigned short* __restrict__ Vt) {
    const int proj = blockIdx.z;
    const float* A = (proj == 0) ? left : right;
    const unsigned short* Wn = Wt + (size_t)proj * 1024 * 1024;
    const int m0 = blockIdx.x * 128;
    const int n0 = blockIdx.y * 128;

    __shared__ unsigned short As[128][40];
    __shared__ unsigned short Bs[128][40];

    const int tid = threadIdx.x;
    const int lane = tid & 63, w = tid >> 6;
    const int wm = (w >> 1) * 64, wn = (w & 1) * 64;

    f32x4 acc[4][4];
    for (int i = 0; i < 4; ++i)
        for (int j = 0; j < 4; ++j) acc[i][j] = {0.f, 0.f, 0.f, 0.f};

    for (int k0 = 0; k0 < 1024; k0 += 32) {
        for (int p = 0; p < 4; ++p) {
            int r = p * 32 + (tid >> 3);
            int c = (tid & 7) * 4;
            float4 v = *reinterpret_cast<const float4*>(
                &A[(size_t)(m0 + r) * 1024 + k0 + c]);
            uint32_t lo = f32_to_bf16(v.x) | ((uint32_t)f32_to_bf16(v.y) << 16);
            uint32_t hi = f32_to_bf16(v.z) | ((uint32_t)f32_to_bf16(v.w) << 16);
            *reinterpret_cast<uint2*>(&As[r][c]) = make_uint2(lo, hi);
        }
        for (int cc = 0; cc < 2; ++cc) {
            int idx = tid * 2 + cc;
            int n = idx >> 2, ch = (idx & 3) * 8;
            bf16x8 v = *reinterpret_cast<const bf16x8*>(
                &Wn[(size_t)(n0 + n) * 1024 + k0 + ch]);
            *reinterpret_cast<bf16x8*>(&Bs[n][ch]) = v;
        }
        __syncthreads();
        bf16x8 af[4], bfr[4];
        for (int i = 0; i < 4; ++i)
            af[i] = *reinterpret_cast<const bf16x8*>(
                &As[wm + i * 16 + (lane & 15)][(lane >> 4) * 8]);
        for (int j = 0; j < 4; ++j)
            bfr[j] = *reinterpret_cast<const bf16x8*>(
                &Bs[wn + j * 16 + (lane & 15)][(lane >> 4) * 8]);
        for (int i = 0; i < 4; ++i)
            for (int j = 0; j < 4; ++j)
                acc[i][j] = __builtin_amdgcn_mfma_f32_16x16x32_bf16(
                    af[i], bfr[j], acc[i][j], 0, 0, 0);
        __syncthreads();
    }

    if (proj < 2) {
        unsigned short* Out = (proj == 0) ? Qb : Kb;
        for (int i = 0; i < 4; ++i)
            for (int j = 0; j < 4; ++j) {
                int col = n0 + wn + j * 16 + (lane & 15);
                int row = m0 + wm + i * 16 + (lane >> 4) * 4;
                for (int r = 0; r < 4; ++r)
                    Out[(size_t)(row + r) * 1024 + col] = f32_to_bf16(acc[i][j][r]);
            }
    } else {
        for (int i = 0; i < 4; ++i)
            for (int j = 0; j < 4; ++j) {
                int col = n0 + wn + j * 16 + (lane & 15);
                int row = m0 + wm + i * 16 + (lane >> 4) * 4;
                int b = row >> 12, jj = row & 4095;
                uint32_t lo = f32_to_bf16(acc[i][j][0]) |
                              ((uint32_t)f32_to_bf16(acc[i][j][1]) << 16);
                uint32_t hi = f32_to_bf16(acc[i][j][2]) |
                              ((uint32_t)f32_to_bf16(acc[i][j][3]) << 16);
                *reinterpret_cast<uint2*>(
                    &Vt[((size_t)b * 1024 + col) * 4096 + jj]) = make_uint2(lo, hi);
            }
    }
}

__global__ __launch_bounds__(256, 2) void pv_gemm(
    const unsigned short* __restrict__ P,
    const unsigned short* __restrict__ Vt,
    const float* __restrict__ left,
    float* __restrict__ out) {
    const int m0 = blockIdx.x * 128, n0 = blockIdx.y * 128;

    __shared__ unsigned short As[128 * 32];
    __shared__ unsigned short Bs[128 * 32];

    const int tid = threadIdx.x;
    const int lane = tid & 63, w = tid >> 6;
    const int wm = (w >> 1) * 64, wn = (w & 1) * 64;

    f32x4 acc[4][4];
    for (int i = 0; i < 4; ++i)
        for (int j = 0; j < 4; ++j) acc[i][j] = {0.f, 0.f, 0.f, 0.f};

    gemm_core<4096, 4096, 4096>(P, Vt, As, Bs, m0, n0, acc);

    for (int i = 0; i < 4; ++i)
        for (int j = 0; j < 4; ++j) {
            int col = n0 + wn + j * 16 + (lane & 15);
            int row = m0 + wm + i * 16 + (lane >> 4) * 4;
            for (int r = 0; r < 4; ++r) {
                size_t off = (size_t)(row + r) * 1024 + col;
                out[off] = acc[i][j][r] + left[off];
            }
        }
}

// ---------------------------------------------------------------------------
extern "C" void kernel_launch(void* const* d_in, const int* in_sizes, int n_in,
                              void* d_out, int out_size, void* d_ws, size_t ws_size,
                              hipStream_t stream) {
    const float* left  = (const float*)d_in[0];
    const float* right = (const float*)d_in[1];
    const float* Wq    = (const float*)d_in[2];
    const float* Wk    = (const float*)d_in[3];
    const float* Wv    = (const float*)d_in[4];
    float* out = (float*)d_out;

    // layout: Wt 6MB | Qb 32MB | Kb 32MB | Vt 32MB | S 128MB (Xl/Xr overlay S)
    char* ws = (char*)d_ws;
    unsigned short* Wt = (unsigned short*)ws;
    unsigned short* Qb = (unsigned short*)(ws + 6291456);
    unsigned short* Kb = Qb + (size_t)16384 * 1024;
    unsigned short* Vt = Kb + (size_t)16384 * 1024;
    unsigned short* Sb = Vt + (size_t)16384 * 1024;
    unsigned short* Xl = Sb;                 // dead once qk starts
    unsigned short* Xr = Sb + 16777216;

    const bool batched = ws_size >= 241172480ull; // 6MB + 3*32MB + 128MB

    wtrans_kernel<<<dim3(32, 32, 3), dim3(32, 8), 0, stream>>>(Wq, Wk, Wv, Wt);

    if (batched) {
        conv_bf16<<<4096, 256, 0, stream>>>(left, right, Xl, Xr);
        proj256<<<dim3(64, 4, 3), 512, 0, stream>>>(Xl, Xr, Wt, Qb, Kb, Vt);
        qk128<<<dim3(32, 32, 4), 256, 0, stream>>>(Qb, Kb, Sb);
        softmax_rows<<<4096, 256, 0, stream>>>(Sb);
        pv256<<<dim3(16, 4, 4), 512, 0, stream>>>(Sb, Vt, left, out);
    } else {
        proj_gemm<<<dim3(128, 8, 3), 256, 0, stream>>>(left, right, Wt, Qb, Kb, Vt);
        for (int b = 0; b < 4; ++b) {
            qk128<<<dim3(32, 32, 1), 256, 0, stream>>>(
                Qb + (size_t)b * 4194304, Kb + (size_t)b * 4194304, Sb);
            softmax_rows<<<1024, 256, 0, stream>>>(Sb);
            pv_gemm<<<dim3(32, 8, 1), 256, 0, stream>>>(
                Sb, Vt + (size_t)b * 4194304,
                left + (size_t)b * 4194304, out + (size_t)b * 4194304);
        }
    }
}

// Round 20
// 443.924 us; speedup vs baseline: 4.6835x; 1.0532x over previous
//
#include <hip/hip_runtime.h>
#include <hip/hip_bf16.h>
#include <stdint.h>

typedef short bf16x8 __attribute__((ext_vector_type(8)));
typedef float f32x4 __attribute__((ext_vector_type(4)));

static __device__ __forceinline__ unsigned short f32_to_bf16(float f) {
    union { float f; uint32_t u; } v; v.f = f;
    uint32_t u = v.u;
    uint32_t r = (u + 0x7FFFu + ((u >> 16) & 1u)) >> 16;
    return (unsigned short)r;
}

static __device__ __forceinline__ float bf16_to_f32(unsigned short s) {
    union { uint32_t u; float f; } c; c.u = ((uint32_t)s) << 16;
    return c.f;
}

// async global->LDS, 16B per lane (linear LDS dest: wave-uniform base + lane*16)
static __device__ __forceinline__ void gload_lds16(const unsigned short* g,
                                                   unsigned short* l) {
    __builtin_amdgcn_global_load_lds(
        (const __attribute__((address_space(1))) uint32_t*)g,
        (__attribute__((address_space(3))) uint32_t*)l, 16, 0, 0);
}

// barrier + compiler-level fence (s_barrier alone is not an IR memory fence).
static __device__ __forceinline__ void barrier_fenced() {
    __builtin_amdgcn_s_barrier();
    __builtin_amdgcn_sched_barrier(0);
    asm volatile("" ::: "memory");
}

// ---------------------------------------------------------------------------
// Kernel: convert fp32 -> bf16 (left, right), vectorized.
// ---------------------------------------------------------------------------
__global__ __launch_bounds__(256) void conv_bf16(
    const float* __restrict__ a, const float* __restrict__ b,
    unsigned short* __restrict__ oa, unsigned short* __restrict__ ob) {
    size_t i = ((size_t)blockIdx.x * 256 + threadIdx.x) * 4;
    const size_t stride = (size_t)gridDim.x * 256 * 4;
    for (; i < 16777216; i += stride) {
        float4 v = *reinterpret_cast<const float4*>(a + i);
        ushort4 o;
        o.x = f32_to_bf16(v.x); o.y = f32_to_bf16(v.y);
        o.z = f32_to_bf16(v.z); o.w = f32_to_bf16(v.w);
        *reinterpret_cast<ushort4*>(oa + i) = o;
        float4 u = *reinterpret_cast<const float4*>(b + i);
        ushort4 p;
        p.x = f32_to_bf16(u.x); p.y = f32_to_bf16(u.y);
        p.z = f32_to_bf16(u.z); p.w = f32_to_bf16(u.w);
        *reinterpret_cast<ushort4*>(ob + i) = p;
    }
}

// ---------------------------------------------------------------------------
// Kernel: transpose weights to bf16:  Wt[proj][n][k] = bf16(W[k][n])
// ---------------------------------------------------------------------------
__global__ void wtrans_kernel(const float* __restrict__ Wq,
                              const float* __restrict__ Wk,
                              const float* __restrict__ Wv,
                              unsigned short* __restrict__ Wt) {
    int proj = blockIdx.z;
    const float* W = (proj == 0) ? Wq : (proj == 1 ? Wk : Wv);
    unsigned short* out = Wt + (size_t)proj * 1024 * 1024;
    __shared__ float t[32][33];
    int k0 = blockIdx.x * 32, n0 = blockIdx.y * 32;
    int tx = threadIdx.x, ty = threadIdx.y; // 32 x 8
    for (int r = ty; r < 32; r += 8)
        t[r][tx] = W[(size_t)(k0 + r) * 1024 + n0 + tx];
    __syncthreads();
    for (int r = ty; r < 32; r += 8)
        out[(size_t)(n0 + r) * 1024 + k0 + tx] = f32_to_bf16(t[tx][r]);
}

// ---------------------------------------------------------------------------
// 256x256 GEMM core — round-12 proven dataflow (full-tile dbuf, vmcnt(0)
// drain, ONE fenced barrier per tile). Rotation swizzle: fragment (row,
// 16B-chunk c) stored at chunk position p=(c+row)&7 within the 128-B row
// (0 bank conflicts, verified round 9).
// A: bf16 [M,K] stride lda.  B: bf16 [N,K] stride ldb.  C += A*B^T.
// ---------------------------------------------------------------------------
static __device__ __forceinline__ void gemm256_core(
    const unsigned short* __restrict__ A, const unsigned short* __restrict__ B,
    int K, int lda, int ldb, int m0, int n0,
    unsigned short* lds, f32x4 (&acc)[8][4]) {
    const int tid = threadIdx.x;
    const int lane = tid & 63;
    const int w = tid >> 6;
    const int wm = w >> 2, wn = w & 3;

    const int srow = tid >> 3;                       // 0..63
    const int scol = (((tid & 7) - srow) & 7) * 8;   // shorts
    const unsigned short* ga = A + (size_t)(m0 + srow) * lda + scol;
    const unsigned short* gb = B + (size_t)(n0 + srow) * ldb + scol;
    unsigned short* ldst = lds + tid * 8;

    const int pb = (((lane >> 4) + (lane & 7)) & 7) * 8;
    const int colk0 = pb, colk1 = pb ^ 32;
    const int rA0 = wm * 128 + (lane & 15);
    const int rB0 = wn * 64 + (lane & 15);

    const int NT = K >> 6;

#define STAGE8(gsA, gsB, pA, pB)                                    \
    gload_lds16((gsA), (pA));                                       \
    gload_lds16((gsA) + (size_t)64 * lda, (pA) + 4096);             \
    gload_lds16((gsA) + (size_t)128 * lda, (pA) + 8192);            \
    gload_lds16((gsA) + (size_t)192 * lda, (pA) + 12288);           \
    gload_lds16((gsB), (pB));                                       \
    gload_lds16((gsB) + (size_t)64 * ldb, (pB) + 4096);             \
    gload_lds16((gsB) + (size_t)128 * ldb, (pB) + 8192);            \
    gload_lds16((gsB) + (size_t)192 * ldb, (pB) + 12288);

    STAGE8(ga, gb, ldst, ldst + 16384);
    asm volatile("s_waitcnt vmcnt(0)" ::: "memory");
    barrier_fenced();

    int par = 0;
    for (int t = 0; t < NT; ++t) {
        const unsigned short* rA = lds + par * 32768;
        const unsigned short* rB = rA + 16384;
        bf16x8 a0[4][2], a1[4][2], b0[2][2], b1[2][2];

        if (t + 1 < NT) {
            const unsigned short* gan = ga + (t + 1) * 64;
            const unsigned short* gbn = gb + (t + 1) * 64;
            unsigned short* pA = ldst + (par ^ 1) * 32768;
            STAGE8(gan, gbn, pA, pA + 16384);
        }

#pragma unroll
        for (int mf = 0; mf < 4; ++mf) {
            a0[mf][0] = *reinterpret_cast<const bf16x8*>(
                &rA[(rA0 + mf * 16) * 64 + colk0]);
            a0[mf][1] = *reinterpret_cast<const bf16x8*>(
                &rA[(rA0 + mf * 16) * 64 + colk1]);
        }
#pragma unroll
        for (int nf = 0; nf < 2; ++nf) {
            b0[nf][0] = *reinterpret_cast<const bf16x8*>(
                &rB[(rB0 + nf * 16) * 64 + colk0]);
            b0[nf][1] = *reinterpret_cast<const bf16x8*>(
                &rB[(rB0 + nf * 16) * 64 + colk1]);
        }
        __builtin_amdgcn_s_setprio(1);
#pragma unroll
        for (int mf = 0; mf < 4; ++mf)
#pragma unroll
            for (int nf = 0; nf < 2; ++nf)
#pragma unroll
                for (int ks = 0; ks < 2; ++ks)
                    acc[mf][nf] = __builtin_amdgcn_mfma_f32_16x16x32_bf16(
                        a0[mf][ks], b0[nf][ks], acc[mf][nf], 0, 0, 0);
        __builtin_amdgcn_s_setprio(0);

#pragma unroll
        for (int nf = 0; nf < 2; ++nf) {
            b1[nf][0] = *reinterpret_cast<const bf16x8*>(
                &rB[(rB0 + 32 + nf * 16) * 64 + colk0]);
            b1[nf][1] = *reinterpret_cast<const bf16x8*>(
                &rB[(rB0 + 32 + nf * 16) * 64 + colk1]);
        }
        __builtin_amdgcn_s_setprio(1);
#pragma unroll
        for (int mf = 0; mf < 4; ++mf)
#pragma unroll
            for (int nf = 0; nf < 2; ++nf)
#pragma unroll
                for (int ks = 0; ks < 2; ++ks)
                    acc[mf][2 + nf] = __builtin_amdgcn_mfma_f32_16x16x32_bf16(
                        a0[mf][ks], b1[nf][ks], acc[mf][2 + nf], 0, 0, 0);
        __builtin_amdgcn_s_setprio(0);

#pragma unroll
        for (int mf = 0; mf < 4; ++mf) {
            a1[mf][0] = *reinterpret_cast<const bf16x8*>(
                &rA[(rA0 + 64 + mf * 16) * 64 + colk0]);
            a1[mf][1] = *reinterpret_cast<const bf16x8*>(
                &rA[(rA0 + 64 + mf * 16) * 64 + colk1]);
        }
        __builtin_amdgcn_s_setprio(1);
#pragma unroll
        for (int mf = 0; mf < 4; ++mf)
#pragma unroll
            for (int nf = 0; nf < 2; ++nf)
#pragma unroll
                for (int ks = 0; ks < 2; ++ks)
                    acc[4 + mf][nf] = __builtin_amdgcn_mfma_f32_16x16x32_bf16(
                        a1[mf][ks], b0[nf][ks], acc[4 + mf][nf], 0, 0, 0);
        __builtin_amdgcn_s_setprio(0);

        __builtin_amdgcn_s_setprio(1);
#pragma unroll
        for (int mf = 0; mf < 4; ++mf)
#pragma unroll
            for (int nf = 0; nf < 2; ++nf)
#pragma unroll
                for (int ks = 0; ks < 2; ++ks)
                    acc[4 + mf][2 + nf] = __builtin_amdgcn_mfma_f32_16x16x32_bf16(
                        a1[mf][ks], b1[nf][ks], acc[4 + mf][2 + nf], 0, 0, 0);
        __builtin_amdgcn_s_setprio(0);

        asm volatile("s_waitcnt vmcnt(0)" ::: "memory");
        barrier_fenced();
        par ^= 1;
    }
#undef STAGE8
}

// ---------------------------------------------------------------------------
// proj256: Q = Xl@Wq, K = Xr@Wk, V = Xr@Wv (z = proj). M=16384, N=1024, K=1024.
// ---------------------------------------------------------------------------
__global__ __launch_bounds__(512, 2) void proj256(
    const unsigned short* __restrict__ Xl, const unsigned short* __restrict__ Xr,
    const unsigned short* __restrict__ Wt,
    unsigned short* __restrict__ Qb, unsigned short* __restrict__ Kb,
    unsigned short* __restrict__ Vt) {
    __shared__ unsigned short lds[65536];
    const int proj = blockIdx.z;
    const unsigned short* A = (proj == 0) ? Xl : Xr;
    const unsigned short* B = Wt + (size_t)proj * 1048576;
    const int m0 = blockIdx.x * 256, n0 = blockIdx.y * 256;

    f32x4 acc[8][4];
    for (int i = 0; i < 8; ++i)
        for (int j = 0; j < 4; ++j) acc[i][j] = {0.f, 0.f, 0.f, 0.f};

    gemm256_core(A, B, 1024, 1024, 1024, m0, n0, lds, acc);

    const int lane = threadIdx.x & 63, w = threadIdx.x >> 6;
    const int wm = w >> 2, wn = w & 3;
    if (proj < 2) {
        unsigned short* Out = (proj == 0) ? Qb : Kb;
        for (int mh = 0; mh < 2; ++mh)
            for (int mf = 0; mf < 4; ++mf)
                for (int nh = 0; nh < 2; ++nh)
                    for (int nf = 0; nf < 2; ++nf) {
                        f32x4 v = acc[mh * 4 + mf][nh * 2 + nf];
                        int row = m0 + wm * 128 + mh * 64 + mf * 16 + (lane >> 4) * 4;
                        int col = n0 + wn * 64 + nh * 32 + nf * 16 + (lane & 15);
                        for (int r = 0; r < 4; ++r)
                            Out[(size_t)(row + r) * 1024 + col] = f32_to_bf16(v[r]);
                    }
    } else {
        for (int mh = 0; mh < 2; ++mh)
            for (int mf = 0; mf < 4; ++mf)
                for (int nh = 0; nh < 2; ++nh)
                    for (int nf = 0; nf < 2; ++nf) {
                        f32x4 v = acc[mh * 4 + mf][nh * 2 + nf];
                        int row = m0 + wm * 128 + mh * 64 + mf * 16 + (lane >> 4) * 4;
                        int col = n0 + wn * 64 + nh * 32 + nf * 16 + (lane & 15);
                        int bb = row >> 12, jj = row & 4095;
                        uint32_t lo = f32_to_bf16(v[0]) |
                                      ((uint32_t)f32_to_bf16(v[1]) << 16);
                        uint32_t hi = f32_to_bf16(v[2]) |
                                      ((uint32_t)f32_to_bf16(v[3]) << 16);
                        *reinterpret_cast<uint2*>(
                            &Vt[((size_t)bb * 1024 + col) * 4096 + jj]) =
                            make_uint2(lo, hi);
                    }
    }
}

// ---------------------------------------------------------------------------
// qk256: S[b] = Q[b] @ K[b]^T (bf16 logits). z = batch.
// ---------------------------------------------------------------------------
__global__ __launch_bounds__(512, 2) void qk256(
    const unsigned short* __restrict__ Qb,
    const unsigned short* __restrict__ Kb,
    unsigned short* __restrict__ S) {
    __shared__ unsigned short lds[65536];
    const int b = blockIdx.z;
    const unsigned short* A = Qb + (size_t)b * 4194304;
    const unsigned short* B = Kb + (size_t)b * 4194304;
    unsigned short* Sp = S + (size_t)b * 16777216;
    const int m0 = blockIdx.x * 256, n0 = blockIdx.y * 256;

    f32x4 acc[8][4];
    for (int i = 0; i < 8; ++i)
        for (int j = 0; j < 4; ++j) acc[i][j] = {0.f, 0.f, 0.f, 0.f};

    gemm256_core(A, B, 1024, 1024, 1024, m0, n0, lds, acc);

    const int lane = threadIdx.x & 63, w = threadIdx.x >> 6;
    const int wm = w >> 2, wn = w & 3;
    for (int mh = 0; mh < 2; ++mh)
        for (int mf = 0; mf < 4; ++mf)
            for (int nh = 0; nh < 2; ++nh)
                for (int nf = 0; nf < 2; ++nf) {
                    f32x4 v = acc[mh * 4 + mf][nh * 2 + nf];
                    int row = m0 + wm * 128 + mh * 64 + mf * 16 + (lane >> 4) * 4;
                    int col = n0 + wn * 64 + nh * 32 + nf * 16 + (lane & 15);
                    for (int r = 0; r < 4; ++r)
                        Sp[(size_t)(row + r) * 4096 + col] = f32_to_bf16(v[r]);
                }
}

// ---------------------------------------------------------------------------
// pv256: out[b] = P[b] @ V[b] + left[b]. z = batch. K=4096.
// ---------------------------------------------------------------------------
__global__ __launch_bounds__(512, 2) void pv256(
    const unsigned short* __restrict__ P,
    const unsigned short* __restrict__ Vt,
    const float* __restrict__ left,
    float* __restrict__ out) {
    __shared__ unsigned short lds[65536];
    const int b = blockIdx.z;
    const unsigned short* A = P + (size_t)b * 16777216;
    const unsigned short* B = Vt + (size_t)b * 4194304;
    const float* Lb = left + (size_t)b * 4194304;
    float* Ob = out + (size_t)b * 4194304;
    const int m0 = blockIdx.x * 256, n0 = blockIdx.y * 256;

    f32x4 acc[8][4];
    for (int i = 0; i < 8; ++i)
        for (int j = 0; j < 4; ++j) acc[i][j] = {0.f, 0.f, 0.f, 0.f};

    gemm256_core(A, B, 4096, 4096, 4096, m0, n0, lds, acc);

    const int lane = threadIdx.x & 63, w = threadIdx.x >> 6;
    const int wm = w >> 2, wn = w & 3;
    for (int mh = 0; mh < 2; ++mh)
        for (int mf = 0; mf < 4; ++mf)
            for (int nh = 0; nh < 2; ++nh)
                for (int nf = 0; nf < 2; ++nf) {
                    f32x4 v = acc[mh * 4 + mf][nh * 2 + nf];
                    int row = m0 + wm * 128 + mh * 64 + mf * 16 + (lane >> 4) * 4;
                    int col = n0 + wn * 64 + nh * 32 + nf * 16 + (lane & 15);
                    for (int r = 0; r < 4; ++r) {
                        size_t off = (size_t)(row + r) * 1024 + col;
                        Ob[off] = v[r] + Lb[off];
                    }
                }
}

// ---------------------------------------------------------------------------
// Softmax rows (in-place on bf16 S; scale + 1/l folded).
// ---------------------------------------------------------------------------
__global__ __launch_bounds__(256, 4) void softmax_rows(
    unsigned short* __restrict__ S) {
    const int lane = threadIdx.x & 63;
    const int row = blockIdx.x * 4 + (threadIdx.x >> 6);
    unsigned short* r = S + (size_t)row * 4096;

    float f[64];
    float mx = -INFINITY;
    for (int i = 0; i < 8; ++i) {
        bf16x8 v = *reinterpret_cast<const bf16x8*>(&r[i * 512 + lane * 8]);
        for (int j = 0; j < 8; ++j) {
            float x = bf16_to_f32((unsigned short)v[j]);
            f[i * 8 + j] = x;
            mx = fmaxf(mx, x);
        }
    }
    for (int off = 32; off; off >>= 1) mx = fmaxf(mx, __shfl_xor(mx, off));
    const float ksc = 0.045084220f; // (1/sqrt(1024)) * log2(e)
    float sum = 0.f;
    for (int i = 0; i < 64; ++i) {
        f[i] = exp2f((f[i] - mx) * ksc);
        sum += f[i];
    }
    for (int off = 32; off; off >>= 1) sum += __shfl_xor(sum, off);
    float linv = 1.f / sum;
    for (int i = 0; i < 8; ++i) {
        bf16x8 v;
        for (int j = 0; j < 8; ++j)
            v[j] = (short)f32_to_bf16(f[i * 8 + j] * linv);
        *reinterpret_cast<bf16x8*>(&r[i * 512 + lane * 8]) = v;
    }
}

// ===========================================================================
// Fallback path (ws < 241 MB): round-6 proven kernels.
// ===========================================================================
__global__ __launch_bounds__(256, 4) void proj_gemm(
    const float* __restrict__ left, const float* __restrict__ right,
    const unsigned short* __restrict__ Wt,
    unsigned short* __restrict__ Qb, unsigned short* __restrict__ Kb,
    unsigned short* __restrict__ Vt) {
    const int proj = blockIdx.z;
    const float* A = (proj == 0) ? left : right;
    const unsigned short* Wn = Wt + (size_t)proj * 1024 * 1024;
    const int m0 = blockIdx.x * 128;
    const int n0 = blockIdx.y * 128;

    __shared__ unsigned short As[128][40];
    __shared__ unsigned short Bs[128][40];

    const int tid = threadIdx.x;
    const int lane = tid & 63, w = tid >> 6;
    const int wm = (w >> 1) * 64, wn = (w & 1) * 64;

    f32x4 acc[4][4];
    for (int i = 0; i < 4; ++i)
        for (int j = 0; j < 4; ++j) acc[i][j] = {0.f, 0.f, 0.f, 0.f};

    for (int k0 = 0; k0 < 1024; k0 += 32) {
        for (int p = 0; p < 4; ++p) {
            int r = p * 32 + (tid >> 3);
            int c = (tid & 7) * 4;
            float4 v = *reinterpret_cast<const float4*>(
                &A[(size_t)(m0 + r) * 1024 + k0 + c]);
            uint32_t lo = f32_to_bf16(v.x) | ((uint32_t)f32_to_bf16(v.y) << 16);
            uint32_t hi = f32_to_bf16(v.z) | ((uint32_t)f32_to_bf16(v.w) << 16);
            *reinterpret_cast<uint2*>(&As[r][c]) = make_uint2(lo, hi);
        }
        for (int cc = 0; cc < 2; ++cc) {
            int idx = tid * 2 + cc;
            int n = idx >> 2, ch = (idx & 3) * 8;
            bf16x8 v = *reinterpret_cast<const bf16x8*>(
                &Wn[(size_t)(n0 + n) * 1024 + k0 + ch]);
            *reinterpret_cast<bf16x8*>(&Bs[n][ch]) = v;
        }
        __syncthreads();
        bf16x8 af[4], bfr[4];
        for (int i = 0; i < 4; ++i)
            af[i] = *reinterpret_cast<const bf16x8*>(
                &As[wm + i * 16 + (lane & 15)][(lane >> 4) * 8]);
        for (int j = 0; j < 4; ++j)
            bfr[j] = *reinterpret_cast<const bf16x8*>(
                &Bs[wn + j * 16 + (lane & 15)][(lane >> 4) * 8]);
        for (int i = 0; i < 4; ++i)
            for (int j = 0; j < 4; ++j)
                acc[i][j] = __builtin_amdgcn_mfma_f32_16x16x32_bf16(
                    af[i], bfr[j], acc[i][j], 0, 0, 0);
        __syncthreads();
    }

    if (proj < 2) {
        unsigned short* Out = (proj == 0) ? Qb : Kb;
        for (int i = 0; i < 4; ++i)
            for (int j = 0; j < 4; ++j) {
                int col = n0 + wn + j * 16 + (lane & 15);
                int row = m0 + wm + i * 16 + (lane >> 4) * 4;
                for (int r = 0; r < 4; ++r)
                    Out[(size_t)(row + r) * 1024 + col] = f32_to_bf16(acc[i][j][r]);
            }
    } else {
        for (int i = 0; i < 4; ++i)
            for (int j = 0; j < 4; ++j) {
                int col = n0 + wn + j * 16 + (lane & 15);
                int row = m0 + wm + i * 16 + (lane >> 4) * 4;
                int b = row >> 12, jj = row & 4095;
                uint32_t lo = f32_to_bf16(acc[i][j][0]) |
                              ((uint32_t)f32_to_bf16(acc[i][j][1]) << 16);
                uint32_t hi = f32_to_bf16(acc[i][j][2]) |
                              ((uint32_t)f32_to_bf16(acc[i][j][3]) << 16);
                *reinterpret_cast<uint2*>(
                    &Vt[((size_t)b * 1024 + col) * 4096 + jj]) = make_uint2(lo, hi);
            }
    }
}

template <int K, int LDA, int LDB>
static __device__ __forceinline__ void gemm_core(
    const unsigned short* __restrict__ A, const unsigned short* __restrict__ B,
    unsigned short* As, unsigned short* Bs, int m0, int n0, f32x4 (&acc)[4][4]) {
    const int tid = threadIdx.x;
    const int lane = tid & 63, w = tid >> 6;
    const int wm = (w >> 1) * 64, wn = (w & 1) * 64;
    const int r0 = tid >> 2, c0 = (tid & 3) * 8;

    const unsigned short* a0 = &A[(size_t)(m0 + r0) * LDA + c0];
    const unsigned short* a1 = a0 + (size_t)64 * LDA;
    const unsigned short* b0 = &B[(size_t)(n0 + r0) * LDB + c0];
    const unsigned short* b1 = b0 + (size_t)64 * LDB;
    unsigned short* asl = As + tid * 8;
    unsigned short* bsl = Bs + tid * 8;

    for (int k0 = 0; k0 < K; k0 += 32) {
        gload_lds16(a0 + k0, asl);
        gload_lds16(a1 + k0, asl + 2048);
        gload_lds16(b0 + k0, bsl);
        gload_lds16(b1 + k0, bsl + 2048);
        __syncthreads();
        bf16x8 af[4], bfr[4];
#pragma unroll
        for (int i = 0; i < 4; ++i)
            af[i] = *reinterpret_cast<const bf16x8*>(
                &As[(wm + i * 16 + (lane & 15)) * 32 + (lane >> 4) * 8]);
#pragma unroll
        for (int j = 0; j < 4; ++j)
            bfr[j] = *reinterpret_cast<const bf16x8*>(
                &Bs[(wn + j * 16 + (lane & 15)) * 32 + (lane >> 4) * 8]);
#pragma unroll
        for (int i = 0; i < 4; ++i)
#pragma unroll
            for (int j = 0; j < 4; ++j)
                acc[i][j] = __builtin_amdgcn_mfma_f32_16x16x32_bf16(
                    af[i], bfr[j], acc[i][j], 0, 0, 0);
        __syncthreads();
    }
}

__global__ __launch_bounds__(256, 2) void qk_gemm(
    const unsigned short* __restrict__ Qb,
    const unsigned short* __restrict__ Kb,
    unsigned short* __restrict__ S) {
    const unsigned short* A = Qb;
    const unsigned short* B = Kb;
    const int m0 = blockIdx.x * 128, n0 = blockIdx.y * 128;

    __shared__ unsigned short As[128 * 32];
    __shared__ unsigned short Bs[128 * 32];

    const int tid = threadIdx.x;
    const int lane = tid & 63, w = tid >> 6;
    const int wm = (w >> 1) * 64, wn = (w & 1) * 64;

    f32x4 acc[4][4];
    for (int i = 0; i < 4; ++i)
        for (int j = 0; j < 4; ++j) acc[i][j] = {0.f, 0.f, 0.f, 0.f};

    gemm_core<1024, 1024, 1024>(A, B, As, Bs, m0, n0, acc);

    for (int i = 0; i < 4; ++i)
        for (int j = 0; j < 4; ++j) {
            int col = n0 + wn + j * 16 + (lane & 15);
            int row = m0 + wm + i * 16 + (lane >> 4) * 4;
            for (int r = 0; r < 4; ++r)
                S[(size_t)(row + r) * 4096 + col] = f32_to_bf16(acc[i][j][r]);
        }
}

__global__ __launch_bounds__(256, 2) void pv_gemm(
    const unsigned short* __restrict__ P,
    const unsigned short* __restrict__ Vt,
    const float* __restrict__ left,
    float* __restrict__ out) {
    const int m0 = blockIdx.x * 128, n0 = blockIdx.y * 128;

    __shared__ unsigned short As[128 * 32];
    __shared__ unsigned short Bs[128 * 32];

    const int tid = threadIdx.x;
    const int lane = tid & 63, w = tid >> 6;
    const int wm = (w >> 1) * 64, wn = (w & 1) * 64;

    f32x4 acc[4][4];
    for (int i = 0; i < 4; ++i)
        for (int j = 0; j < 4; ++j) acc[i][j] = {0.f, 0.f, 0.f, 0.f};

    gemm_core<4096, 4096, 4096>(P, Vt, As, Bs, m0, n0, acc);

    for (int i = 0; i < 4; ++i)
        for (int j = 0; j < 4; ++j) {
            int col = n0 + wn + j * 16 + (lane & 15);
            int row = m0 + wm + i * 16 + (lane >> 4) * 4;
            for (int r = 0; r < 4; ++r) {
                size_t off = (size_t)(row + r) * 1024 + col;
                out[off] = acc[i][j][r] + left[off];
            }
        }
}

// ---------------------------------------------------------------------------
extern "C" void kernel_launch(void* const* d_in, const int* in_sizes, int n_in,
                              void* d_out, int out_size, void* d_ws, size_t ws_size,
                              hipStream_t stream) {
    const float* left  = (const float*)d_in[0];
    const float* right = (const float*)d_in[1];
    const float* Wq    = (const float*)d_in[2];
    const float* Wk    = (const float*)d_in[3];
    const float* Wv    = (const float*)d_in[4];
    float* out = (float*)d_out;

    // layout: Wt 6MB | Qb 32MB | Kb 32MB | Vt 32MB | S 128MB (Xl/Xr overlay S)
    char* ws = (char*)d_ws;
    unsigned short* Wt = (unsigned short*)ws;
    unsigned short* Qb = (unsigned short*)(ws + 6291456);
    unsigned short* Kb = Qb + (size_t)16384 * 1024;
    unsigned short* Vt = Kb + (size_t)16384 * 1024;
    unsigned short* Sb = Vt + (size_t)16384 * 1024;
    unsigned short* Xl = Sb;                 // dead once qk starts
    unsigned short* Xr = Sb + 16777216;

    const bool batched = ws_size >= 241172480ull; // 6MB + 3*32MB + 128MB

    wtrans_kernel<<<dim3(32, 32, 3), dim3(32, 8), 0, stream>>>(Wq, Wk, Wv, Wt);

    if (batched) {
        conv_bf16<<<4096, 256, 0, stream>>>(left, right, Xl, Xr);
        proj256<<<dim3(64, 4, 3), 512, 0, stream>>>(Xl, Xr, Wt, Qb, Kb, Vt);
        qk256<<<dim3(16, 16, 4), 512, 0, stream>>>(Qb, Kb, Sb);
        softmax_rows<<<4096, 256, 0, stream>>>(Sb);
        pv256<<<dim3(16, 4, 4), 512, 0, stream>>>(Sb, Vt, left, out);
    } else {
        proj_gemm<<<dim3(128, 8, 3), 256, 0, stream>>>(left, right, Wt, Qb, Kb, Vt);
        for (int b = 0; b < 4; ++b) {
            qk_gemm<<<dim3(32, 32, 1), 256, 0, stream>>>(
                Qb + (size_t)b * 4194304, Kb + (size_t)b * 4194304, Sb);
            softmax_rows<<<1024, 256, 0, stream>>>(Sb);
            pv_gemm<<<dim3(32, 8, 1), 256, 0, stream>>>(
                Sb, Vt + (size_t)b * 4194304,
                left + (size_t)b * 4194304, out + (size_t)b * 4194304);
        }
    }
}